// Round 3
// baseline (244.487 us; speedup 1.0000x reference)
//
#include <hip/hip_runtime.h>

// QuantizedBKCore: tridiagonal resolvent diagonal via two continued-fraction
// sweeps, bit-exact vs numpy float32/complex64 reference (validated R1/R2:
// absmax == 0 with Smith division, contract(off), rintf, exact op order).
//
// R3: R1/R2 both 171us, latency-bound on the serial chain + scattered loads +
// (R2) scratch spill of the R array. Changes:
//  - per-block LDS staging of negA (coalesced v read, neg_a computed ONCE),
//  - cc = hsub*hsup precomputed to d_ws by a prologue kernel,
//  - SEG=32, R in registers; block = 256 lanes = 256 consecutive segments of
//    one 8192-elem chunk of one row.

#define SEG   32               // elements per lane
#define WARM  64               // warmup steps (two-step contraction <= 1/4)
#define CHUNK 8192             // elements per block (= 256 segments)
#define HALO  64               // warmup halo on each side
#define STAGE (CHUNK + 2*HALO) // 8320 staged floats
#define SPAD  (STAGE + STAGE/32) // +1 pad per 32: lane stride 33 -> no conflicts

struct C2 { float r, i; };

__device__ __forceinline__ int padi(int i) { return i + (i >> 5); }

// numpy CFLOAT_divide (Smith), numerator (nr, 0), no FMA contraction.
__device__ __forceinline__ C2 npdiv(float nr, float dr, float di) {
  #pragma clang fp contract(off)
  const bool  b   = fabsf(dr) >= fabsf(di);
  const float num = b ? di : dr;
  const float den = b ? dr : di;
  const float rat = num / den;          // IEEE-correct div
  const float t   = num * rat;
  const float s   = den + t;            // mul + add, NOT fma
  const float scl = 1.0f / s;           // IEEE-correct div
  const float u   = nr * scl;
  const float m   = nr * rat;
  const float w   = m * scl;
  C2 o;
  o.r = b ? u : w;
  o.i = b ? -w : -u;                    // sign-of-product flip is exact
  return o;
}

// -(clip(h0_diag + fake_quantize(v), -10, 10)); exact op order.
__device__ __forceinline__ float neg_a(float vv, float hd) {
  #pragma clang fp contract(off)
  float q = rintf(vv);                  // round half-even == np.rint
  q = fminf(fmaxf(q, -128.0f), 127.0f);
  float he = hd + q;
  he = fminf(fmaxf(he, -10.0f), 10.0f);
  return 0.0f - he;                     // Re(z - a)
}

// clip(+-100) -> rint -> clip(+-128); exact ops.
__device__ __forceinline__ float fq_out(float x) {
  #pragma clang fp contract(off)
  x = fminf(fmaxf(x, -100.0f), 100.0f);
  x = rintf(x);
  x = fminf(fmaxf(x, -128.0f), 127.0f);
  return x;
}

__global__ void cc_kernel(const float* __restrict__ hsub,
                          const float* __restrict__ hsup,
                          float* __restrict__ cc, int n) {
  #pragma clang fp contract(off)
  const int i = blockIdx.x * blockDim.x + threadIdx.x;
  if (i < n) cc[i] = hsub[i] * hsup[i];
}

__global__ void __launch_bounds__(256, 4)
bk_kernel(const float* __restrict__ v,
          const float* __restrict__ hdiag,
          const float* __restrict__ cc,     // (N-1) precomputed couplings
          float2* __restrict__ out,
          int N, int chunks_per_row) {
  #pragma clang fp contract(off)
  __shared__ float sA[SPAD];              // 34,320 B -> 4 blocks/CU

  const int row  = blockIdx.x / chunks_per_row;
  const int ch   = blockIdx.x - row * chunks_per_row;
  const int base = ch * CHUNK;
  const long rowoff = (long)row * N;

  // ---- stage negA for k in [base-HALO, base-HALO+STAGE), coalesced --------
  for (int i = threadIdx.x; i < STAGE; i += 256) {
    const int k = base - HALO + i;
    float na = 0.0f;
    if (k >= 0 && k < N) na = neg_a(v[rowoff + k], hdiag[k]);
    sA[padi(i)] = na;
  }
  __syncthreads();

  const int s0 = base + threadIdx.x * SEG;
  if (s0 >= N) return;                    // after the barrier: safe
  const int s1  = s0 + SEG;
  const int li0 = threadIdx.x * SEG + HALO;  // sA index (unpadded) of s0

  float cr, ci;

  // ---- backward sweep: R into registers -----------------------------------
  // R[N-1]=0; R[k-1] = c[k-1] / (z - a[k] - R[k])
  float Rr[SEG], Ri[SEG];
  cr = 0.0f; ci = 0.0f;                   // exact R[N-1] when warmup is empty
  const int j1 = min(s1 - 1 + WARM, N - 1);
  #pragma unroll 4
  for (int k = j1; k >= s1; --k) {        // warmup (contraction bit-merges)
    const float negA = sA[padi(k - base + HALO)];
    const float ccv  = cc[k - 1];
    const float dr = negA - cr;
    const float di = 1.0f - ci;
    const C2 nc = npdiv(ccv, dr, di);
    cr = nc.r; ci = nc.i;
  }
  Rr[SEG-1] = cr; Ri[SEG-1] = ci;         // R[s1-1]
  #pragma unroll
  for (int t = SEG - 1; t >= 1; --t) {
    const int k = s0 + t;
    if (k < N) {                          // partial-tail guard (no-op here)
      const float negA = sA[padi(li0 + t)];
      const float ccv  = cc[k - 1];
      const float dr = negA - cr;
      const float di = 1.0f - ci;
      const C2 nc = npdiv(ccv, dr, di);
      cr = nc.r; ci = nc.i;
    }
    Rr[t-1] = cr; Ri[t-1] = ci;
  }

  // ---- forward sweep + combine + store ------------------------------------
  // L[0]=0; L[k+1] = c[k] / (z - a[k] - L[k]);  G = 1 / (((z-a) - L) - R)
  cr = 0.0f; ci = 0.0f;                   // exact L[0] when warmup is empty
  const int k0 = max(s0 - WARM, 0);
  #pragma unroll 4
  for (int k = k0; k < s0; ++k) {         // warmup
    const float negA = sA[padi(k - base + HALO)];
    const float ccv  = cc[k];
    const float dr = negA - cr;
    const float di = 1.0f - ci;
    const C2 nc = npdiv(ccv, dr, di);
    cr = nc.r; ci = nc.i;
  }
  #pragma unroll
  for (int t = 0; t < SEG; ++t) {
    const int k = s0 + t;
    if (k < N) {
      const float negA = sA[padi(li0 + t)];
      const float drL = negA - cr;        // (z - a) - L
      const float diL = 1.0f - ci;
      const float drf = drL - Rr[t];      // ... - R
      const float dif = diL - Ri[t];
      const C2 G = npdiv(1.0f, drf, dif);
      out[rowoff + k] = make_float2(fq_out(G.r), fq_out(G.i));
      if (t < SEG - 1 && k + 1 < N) {     // advance L
        const float ccv = cc[k];
        const C2 nc = npdiv(ccv, drL, diL);
        cr = nc.r; ci = nc.i;
      }
    }
  }
}

extern "C" void kernel_launch(void* const* d_in, const int* in_sizes, int n_in,
                              void* d_out, int out_size, void* d_ws, size_t ws_size,
                              hipStream_t stream) {
  const float* v    = (const float*)d_in[0];
  const float* hd   = (const float*)d_in[1];
  const float* hsub = (const float*)d_in[2];
  const float* hsup = (const float*)d_in[3];
  const int N = in_sizes[1];
  const int B = in_sizes[0] / N;
  const int chunks = (N + CHUNK - 1) / CHUNK;   // 2 for N=16384

  float* cc = (float*)d_ws;                     // N-1 floats scratch
  cc_kernel<<<(N - 1 + 255) / 256, 256, 0, stream>>>(hsub, hsup, cc, N - 1);
  bk_kernel<<<B * chunks, 256, 0, stream>>>(v, hd, cc, (float2*)d_out,
                                            N, chunks);
}

// Round 4
// 185.676 us; speedup vs baseline: 1.3167x; 1.3167x over previous
//
#include <hip/hip_runtime.h>

// QuantizedBKCore: tridiagonal resolvent diagonal via two continued-fraction
// sweeps, bit-exact vs numpy float32/complex64 reference (validated R1-R3:
// absmax == 0 with Smith division, contract(off), rintf, exact op order).
//
// R4: R1-R3 all ~172us. Diagnosis: (a) R-array register spill (R3 VGPR=52,
// WRITE 564MB scratch traffic), (b) scattered VMEM (cc loads, G stores at
// 256B lane stride) saturating the TA pipe while VALU sat at 37%.
// Fixes: negA AND cc staged in LDS; fixed-trip (64) warmup loops over
// zero-staged halos (fake cc=0 steps keep carry at (+-0,-+0), bit-transparent
// to the first real step); VGPR cap 256 so Rr/Ri[32] stay in registers;
// G staged into the dead sA/sC slots and flushed coalesced (stride-1).
// Steady-state step touches only LDS + registers. d_ws unused.

#define SEG   32                  // elements per lane
#define WARM  64                  // warmup steps (two-step contraction <= 1/4)
#define LANES 128                 // threads per block (2 waves)
#define CHUNK (LANES*SEG)         // 4096 elements per block
#define HALO  WARM
#define STAGE (CHUNK + 2*HALO)    // 4224 staged values per array
#define SPAD  (STAGE + STAGE/32 + 1)  // stride-33 padding: conflict-free

struct C2 { float r, i; };

__device__ __forceinline__ int padi(int i) { return i + (i >> 5); }

// numpy CFLOAT_divide (Smith), numerator (nr, 0), no FMA contraction.
__device__ __forceinline__ C2 npdiv(float nr, float dr, float di) {
  #pragma clang fp contract(off)
  const bool  b   = fabsf(dr) >= fabsf(di);
  const float num = b ? di : dr;
  const float den = b ? dr : di;
  const float rat = num / den;          // IEEE-correct div
  const float t   = num * rat;
  const float s   = den + t;            // mul + add, NOT fma
  const float scl = 1.0f / s;           // IEEE-correct div
  const float u   = nr * scl;
  const float m   = nr * rat;
  const float w   = m * scl;
  C2 o;
  o.r = b ? u : w;
  o.i = b ? -w : -u;                    // sign-of-product flip is exact
  return o;
}

// -(clip(h0_diag + fake_quantize(v), -10, 10)); exact op order.
__device__ __forceinline__ float neg_a(float vv, float hd) {
  #pragma clang fp contract(off)
  float q = rintf(vv);                  // round half-even == np.rint
  q = fminf(fmaxf(q, -128.0f), 127.0f);
  float he = hd + q;
  he = fminf(fmaxf(he, -10.0f), 10.0f);
  return 0.0f - he;                     // Re(z - a)
}

// clip(+-100) -> rint -> clip(+-128); exact ops.
__device__ __forceinline__ float fq_out(float x) {
  #pragma clang fp contract(off)
  x = fminf(fmaxf(x, -100.0f), 100.0f);
  x = rintf(x);
  x = fminf(fmaxf(x, -128.0f), 127.0f);
  return x;
}

__global__ void __launch_bounds__(LANES, 2)   // VGPR cap 256: no spill
bk_kernel(const float* __restrict__ v,
          const float* __restrict__ hdiag,
          const float* __restrict__ hsub,
          const float* __restrict__ hsup,
          float2* __restrict__ out,
          int N, int chunks_per_row) {
  #pragma clang fp contract(off)
  __shared__ float sA[SPAD];   // negA, later G.real
  __shared__ float sC[SPAD];   // cc,   later G.imag

  const int tid  = threadIdx.x;
  const int row  = blockIdx.x / chunks_per_row;
  const int ch   = blockIdx.x - row * chunks_per_row;
  const int base = ch * CHUNK;
  const long rowoff = (long)row * N;

  // ---- stage negA + cc, coalesced; zeros outside [0,N) ---------------------
  for (int i = tid; i < STAGE; i += LANES) {
    const int k = base - HALO + i;
    float na = 0.0f, cv = 0.0f;
    if (k >= 0 && k < N)     na = neg_a(v[rowoff + k], hdiag[k]);
    if (k >= 0 && k < N - 1) cv = hsub[k] * hsup[k];
    sA[padi(i)] = na;
    sC[padi(i)] = cv;
  }
  __syncthreads();

  const int li0 = tid * SEG + HALO;     // sA/sC (unpadded) index of s0

  float Rr[SEG], Ri[SEG];
  float cr, ci;

  // ---- backward sweep ------------------------------------------------------
  // R[N-1]=0; R[k-1] = c[k-1] / (z - a[k] - R[k]).  Fixed 64-step warmup from
  // carry=0 over zero-staged halo: fake steps (cc=0) keep carry bit-transparent.
  cr = 0.0f; ci = 0.0f;
  #pragma unroll 4
  for (int w2 = 0; w2 < WARM; ++w2) {
    const int i = li0 + SEG + (WARM - 1) - w2;   // k = s1+63 .. s1
    const float negA = sA[padi(i)];
    const float ccv  = sC[padi(i - 1)];          // cc[k-1]
    const float dr = negA - cr;
    const float di = 1.0f - ci;
    const C2 nc = npdiv(ccv, dr, di);
    cr = nc.r; ci = nc.i;
  }
  Rr[SEG-1] = cr; Ri[SEG-1] = ci;                // R[s1-1]
  #pragma unroll
  for (int t = SEG - 1; t >= 1; --t) {
    const int i = li0 + t;
    const float negA = sA[padi(i)];
    const float ccv  = sC[padi(i - 1)];
    const float dr = negA - cr;
    const float di = 1.0f - ci;
    const C2 nc = npdiv(ccv, dr, di);
    cr = nc.r; ci = nc.i;
    Rr[t-1] = cr; Ri[t-1] = ci;
  }

  // ---- forward warmup ------------------------------------------------------
  // L[0]=0; L[k+1] = c[k] / (z - a[k] - L[k])
  cr = 0.0f; ci = 0.0f;
  #pragma unroll 4
  for (int w2 = 0; w2 < WARM; ++w2) {
    const int i = li0 - WARM + w2;               // k = s0-64 .. s0-1
    const float negA = sA[padi(i)];
    const float ccv  = sC[padi(i)];              // cc[k]
    const float dr = negA - cr;
    const float di = 1.0f - ci;
    const C2 nc = npdiv(ccv, dr, di);
    cr = nc.r; ci = nc.i;
  }
  __syncthreads();   // all cross-lane warmup reads done before G overwrites

  // ---- forward main: combine, stage G into dead sA/sC slots, advance L ----
  #pragma unroll
  for (int t = 0; t < SEG; ++t) {
    const int pi = padi(li0 + t);
    const float negA = sA[pi];
    const float ccv  = sC[pi];
    const float drL = negA - cr;                 // (z - a) - L
    const float diL = 1.0f - ci;
    const float drf = drL - Rr[t];               // ... - R
    const float dif = diL - Ri[t];
    const C2 G = npdiv(1.0f, drf, dif);
    sA[pi] = fq_out(G.r);                        // slot dead after this step
    sC[pi] = fq_out(G.i);
    if (t < SEG - 1) {                           // advance L within segment
      const C2 nc = npdiv(ccv, drL, diL);
      cr = nc.r; ci = nc.i;
    }
  }
  __syncthreads();

  // ---- coalesced flush: stride-1 float2 stores (512 B per wave-instr) -----
  for (int j = tid; j < CHUNK; j += LANES) {
    const int pj = padi(j + HALO);
    out[rowoff + base + j] = make_float2(sA[pj], sC[pj]);
  }
}

extern "C" void kernel_launch(void* const* d_in, const int* in_sizes, int n_in,
                              void* d_out, int out_size, void* d_ws, size_t ws_size,
                              hipStream_t stream) {
  const float* v    = (const float*)d_in[0];
  const float* hd   = (const float*)d_in[1];
  const float* hsub = (const float*)d_in[2];
  const float* hsup = (const float*)d_in[3];
  const int N = in_sizes[1];
  const int B = in_sizes[0] / N;
  const int chunks = (N + CHUNK - 1) / CHUNK;    // 4 for N=16384
  bk_kernel<<<B * chunks, LANES, 0, stream>>>(v, hd, hsub, hsup,
                                              (float2*)d_out, N, chunks);
}